// Round 12
// baseline (1051.820 us; speedup 1.0000x reference)
//
#include <hip/hip_runtime.h>
#include <math.h>

static constexpr int N = 20000;       // nodes
static constexpr int E = 8192;        // hyperedges
static constexpr int F = 128;         // feature dim
static constexpr int NP = 20480;      // padded node count (K for gemmB; 1024*20)
static constexpr int NP2 = 20096;     // padded node count for gemmC output planes (157*128)
static constexpr int PREP_BLOCKS = 1024;  // 20 rows each; blocks >= 1000 are pad
static constexpr int PREP_REAL = 1000;
static constexpr int XW_BLOCKS = NP / 8;  // 2560, 8 rows each
static constexpr int SE_BLOCKS = 128;     // folded into gemmB launch (blocks 0..127)
static constexpr int KS_B = 8;        // gemmB split-K
static constexpr int KS_C = 4;        // gemmC split-K
static constexpr int PREP_REP = 3;    // MEASUREMENT: x3 rep of prep_xw to surface it in top-5

typedef short bf16x8 __attribute__((ext_vector_type(8)));
typedef float f32x4 __attribute__((ext_vector_type(4)));

__device__ __forceinline__ float gelu_erf(float x) {
    return 0.5f * x * (1.0f + erff(x * 0.70710678118654752440f));
}
__device__ __forceinline__ ushort f2bf(float f) {
    unsigned u = __float_as_uint(f);
    return (ushort)((u + 0x7FFFu + ((u >> 16) & 1u)) >> 16);
}
// async global->LDS, 16B per lane (global source per-lane, LDS dest = base + lane*16)
__device__ __forceinline__ void gload16(const void* g, void* lds) {
    __builtin_amdgcn_global_load_lds(
        (const __attribute__((address_space(1))) unsigned int*)g,
        (__attribute__((address_space(3))) unsigned int*)lds, 16, 0, 0);
}

// ---------------- fused: prep (blocks 0..1023) + xw->yT (blocks 1024..3583) ----------------
// MEASUREMENT ROUND: whole body repeated PREP_REP times (identical work each rep) so this
// dispatch exceeds the ~400us harness fills and appears in the rocprof top-5. true cost = dur/3.
__global__ __launch_bounds__(256) void k_prep_xw(const float* __restrict__ H,
                                                 float* __restrict__ DeP,
                                                 ushort* __restrict__ Hbs,
                                                 const float* __restrict__ x,
                                                 const float* __restrict__ lin_w,
                                                 const float* __restrict__ lin_b,
                                                 ushort* __restrict__ yT) {
    __shared__ __align__(16) char smem[4096];
    const int tid = threadIdx.x;

    for (int rep = 0; rep < PREP_REP; ++rep) {
    if (blockIdx.x < PREP_BLOCKS) {
        // ================= prep =================
        const int lane = tid & 63, wid = tid >> 6;
        const int r0 = blockIdx.x * 20;
        if (r0 >= N) {        // pad rows [N, NP): Hbs = 0
            uint4 z = make_uint4(0, 0, 0, 0);
            for (int r = 0; r < 20; ++r) {
                ushort* orow = Hbs + (size_t)(r0 + r) * E;
#pragma unroll
                for (int j = 0; j < 4; ++j) *(uint4*)(orow + (j * 256 + tid) * 8) = z;
            }
            continue;
        }
        float (*rp)[4] = (float(*)[4])smem;    // [20][4]
        float4 ca[4][2];
#pragma unroll
        for (int j = 0; j < 4; ++j) {
            ca[j][0] = make_float4(0.f, 0.f, 0.f, 0.f);
            ca[j][1] = make_float4(0.f, 0.f, 0.f, 0.f);
        }
        for (int r = 0; r < 20; ++r) {
            const float* row = H + (size_t)(r0 + r) * E;
            float4 va[4], vb[4];
            float rs = 0.f;
#pragma unroll
            for (int j = 0; j < 4; ++j) {
                const float* base = row + (j * 256 + tid) * 8;   // 32B contiguous per thread
                va[j] = *(const float4*)(base);
                vb[j] = *(const float4*)(base + 4);
                ca[j][0].x += va[j].x; ca[j][0].y += va[j].y; ca[j][0].z += va[j].z; ca[j][0].w += va[j].w;
                ca[j][1].x += vb[j].x; ca[j][1].y += vb[j].y; ca[j][1].z += vb[j].z; ca[j][1].w += vb[j].w;
                rs += (va[j].x + va[j].y) + (va[j].z + va[j].w);
                rs += (vb[j].x + vb[j].y) + (vb[j].z + vb[j].w);
            }
#pragma unroll
            for (int off = 32; off > 0; off >>= 1) rs += __shfl_xor(rs, off, 64);
            if (lane == 0) rp[r][wid] = rs;
            __syncthreads();
            float scale = rsqrtf(fmaxf(rp[r][0] + rp[r][1] + rp[r][2] + rp[r][3], 1.f));
            ushort* orow = Hbs + (size_t)(r0 + r) * E;
#pragma unroll
            for (int j = 0; j < 4; ++j) {
                uint4 o;
                o.x = (unsigned)f2bf(va[j].x * scale) | ((unsigned)f2bf(va[j].y * scale) << 16);
                o.y = (unsigned)f2bf(va[j].z * scale) | ((unsigned)f2bf(va[j].w * scale) << 16);
                o.z = (unsigned)f2bf(vb[j].x * scale) | ((unsigned)f2bf(vb[j].y * scale) << 16);
                o.w = (unsigned)f2bf(vb[j].z * scale) | ((unsigned)f2bf(vb[j].w * scale) << 16);
                *(uint4*)(orow + (j * 256 + tid) * 8) = o;       // 16B contiguous store
            }
        }
        float* dp = DeP + (size_t)blockIdx.x * E;
#pragma unroll
        for (int j = 0; j < 4; ++j) {
            *(float4*)(dp + (j * 256 + tid) * 8) = ca[j][0];
            *(float4*)(dp + (j * 256 + tid) * 8 + 4) = ca[j][1];
        }
        __syncthreads();    // rep seam: rp reuse
    } else {
        // ================= xw -> yT (lin_w read directly, row-contiguous per thread) ======
        const int bxx = blockIdx.x - PREP_BLOCKS;
        const int r0 = bxx * 8;
        if (r0 >= N) {        // pad cols of yT
            if (tid < 128) {
                uint4 z = make_uint4(0, 0, 0, 0);
                *(uint4*)(yT + (size_t)tid * NP + r0) = z;
            }
            continue;
        }
        float* xs = (float*)smem;              // [8][128] fp32
#pragma unroll
        for (int c = 0; c < 4; ++c) {
            int lin = c * 256 + tid;
            xs[lin] = x[(size_t)r0 * F + lin];
        }
        __syncthreads();
        const int f = tid & 127, half = tid >> 7;    // rows half*4 .. half*4+3
        float b = lin_b[f];
        float a0 = b, a1 = b, a2 = b, a3 = b;
        const float* xr = xs + (half * 4) * F;
        const float* lwr = lin_w + (size_t)f * F;
#pragma unroll 4
        for (int k = 0; k < F; k += 4) {
            float4 lw = *(const float4*)(lwr + k);
            a0 += xr[0 * F + k] * lw.x; a0 += xr[0 * F + k + 1] * lw.y;
            a0 += xr[0 * F + k + 2] * lw.z; a0 += xr[0 * F + k + 3] * lw.w;
            a1 += xr[1 * F + k] * lw.x; a1 += xr[1 * F + k + 1] * lw.y;
            a1 += xr[1 * F + k + 2] * lw.z; a1 += xr[1 * F + k + 3] * lw.w;
            a2 += xr[2 * F + k] * lw.x; a2 += xr[2 * F + k + 1] * lw.y;
            a2 += xr[2 * F + k + 2] * lw.z; a2 += xr[2 * F + k + 3] * lw.w;
            a3 += xr[3 * F + k] * lw.x; a3 += xr[3 * F + k + 1] * lw.y;
            a3 += xr[3 * F + k + 2] * lw.z; a3 += xr[3 * F + k + 3] * lw.w;
        }
        __syncthreads();                        // all xs reads done
        ushort* tile = (ushort*)smem;           // [8][128] bf16
        tile[(half * 4 + 0) * F + f] = f2bf(a0);
        tile[(half * 4 + 1) * F + f] = f2bf(a1);
        tile[(half * 4 + 2) * F + f] = f2bf(a2);
        tile[(half * 4 + 3) * F + f] = f2bf(a3);
        __syncthreads();
        if (tid < 128) {
            unsigned u[4];
#pragma unroll
            for (int qq = 0; qq < 4; ++qq) {
                ushort lo = tile[(qq * 2 + 0) * F + tid];
                ushort hi = tile[(qq * 2 + 1) * F + tid];
                u[qq] = (unsigned)lo | ((unsigned)hi << 16);
            }
            uint4 o = make_uint4(u[0], u[1], u[2], u[3]);
            *(uint4*)(yT + (size_t)tid * NP + r0) = o;
        }
        __syncthreads();    // rep seam: smem reuse (waves w/ tid>=128 must not overwrite xs early)
    }
    }  // rep
}

// ---------------- tsT[f][e] = bf16(se[e] * sum_ks tB[ks][e][f])  (reduce + transpose) ------
__global__ void k_tst(const float* __restrict__ tB, const float* __restrict__ se,
                      ushort* __restrict__ tsT) {
    __shared__ __align__(16) char tl[8192];
    int tid = threadIdx.x;
    int r0 = (blockIdx.x >> 1) * 64;   // e
    int c0 = (blockIdx.x & 1) * 64;    // f
#pragma unroll
    for (int c = 0; c < 4; ++c) {
        int lin = c * 256 + tid;
        int row = lin >> 4, ch = lin & 15;
        size_t base = (size_t)(r0 + row) * F + c0 + ch * 4;
        float4 v = make_float4(0.f, 0.f, 0.f, 0.f);
#pragma unroll
        for (int ks = 0; ks < KS_B; ++ks) {
            float4 p = *(const float4*)(tB + (size_t)ks * E * F + base);
            v.x += p.x; v.y += p.y; v.z += p.z; v.w += p.w;
        }
        float s = se[r0 + row];
        ushort4 b;
        b.x = f2bf(v.x * s); b.y = f2bf(v.y * s); b.z = f2bf(v.z * s); b.w = f2bf(v.w * s);
        int key = ((row ^ (row >> 3)) & 7) << 4;
        *(ushort4*)(tl + row * 128 + ((ch * 8) ^ key)) = b;
    }
    __syncthreads();
#pragma unroll
    for (int c = 0; c < 2; ++c) {
        int lin = c * 256 + tid;
        int fl = lin >> 3, vch = lin & 7;
        unsigned u[4];
#pragma unroll
        for (int qq = 0; qq < 4; ++qq) {
            int r1 = vch * 8 + qq * 2, r2 = r1 + 1;
            ushort a = *(const ushort*)(tl + r1 * 128 + ((fl * 2) ^ (((r1 ^ (r1 >> 3)) & 7) << 4)));
            ushort b = *(const ushort*)(tl + r2 * 128 + ((fl * 2) ^ (((r2 ^ (r2 >> 3)) & 7) << 4)));
            u[qq] = (unsigned)a | ((unsigned)b << 16);
        }
        uint4 o = make_uint4(u[0], u[1], u[2], u[3]);
        *(uint4*)(tsT + (size_t)(c0 + fl) * E + r0 + vch * 8) = o;
    }
}

// ---------------- gemmB launch: blocks 0..127 = se reduction; 128..639 = gemmB ------------
__global__ __launch_bounds__(256) void k_gemmB(const ushort* __restrict__ Hbs,
                                               const ushort* __restrict__ yT,
                                               float* __restrict__ tB,
                                               const float* __restrict__ DeP,
                                               const float* __restrict__ W,
                                               float* __restrict__ se) {
    __shared__ __align__(16) char lA[2][16384];   // As[e 128][v 64] bf16, key ((e>>3)&7)<<4
    __shared__ __align__(16) char lB[2][16384];   // Bs[f 128][v 64] bf16, key (f&7)<<4
    const int tid = threadIdx.x;

    if (blockIdx.x < SE_BLOCKS) {
        // ===== se reduction (4-way p-split, 4 independent accumulators) =====
        float (*red)[64] = (float(*)[64])lA;
        const int c = blockIdx.x * 64 + (tid & 63);
        const int pg = tid >> 6;
        float s0 = 0.f, s1 = 0.f, s2 = 0.f, s3 = 0.f;
        int p = pg;
        for (; p + 12 < PREP_REAL; p += 16) {
            s0 += DeP[(size_t)(p +  0) * E + c];
            s1 += DeP[(size_t)(p +  4) * E + c];
            s2 += DeP[(size_t)(p +  8) * E + c];
            s3 += DeP[(size_t)(p + 12) * E + c];
        }
        for (; p < PREP_REAL; p += 4) s0 += DeP[(size_t)p * E + c];
        red[pg][tid & 63] = (s0 + s1) + (s2 + s3);
        __syncthreads();
        if (tid < 64) {
            float d = red[0][tid] + red[1][tid] + red[2][tid] + red[3][tid];
            int e = blockIdx.x * 64 + tid;
            se[e] = W[e] / fmaxf(d, 1.f);
        }
        return;
    }

    const int bx2 = blockIdx.x - SE_BLOCKS;
    const int sw = (bx2 & 7) * 64 + (bx2 >> 3);   // bijective (512 % 8 == 0)
    const int m0 = (sw & 63) * 128;    // e tile
    const int ks = sw >> 6;
    const int k0 = ks * 2560;          // v chunk
    const int lane = tid & 63, w = tid >> 6;
    const int wm = (w & 1) * 64, wn = (w >> 1) * 64;
    const int lrow = lane & 15, g16 = (lane >> 4) * 16;
    const int NSTEP = 40;

    const int vq = tid >> 4;
    const int e8 = (tid & 15) * 8;
    const ushort* pa = Hbs + (size_t)(k0 + vq * 4) * E + m0 + e8;
    const int abase = e8 * 128 + ((vq * 8) ^ ((tid & 7) << 4));

    // B staging via global_load_lds: wave w stages f-rows [w*32, w*32+32)
    const int row8 = lane >> 3, ch8 = lane & 7;
    const ushort* gB = yT + (size_t)(w * 32 + row8) * NP + k0 + ((ch8 ^ row8) * 8);
    const int ldstB = w * 32 * 128;

    int aoff[4][2], boff[4][2];
#pragma unroll
    for (int f = 0; f < 4; ++f)
#pragma unroll
        for (int kk = 0; kk < 2; ++kk) {
            int ma = wm + f * 16 + lrow;
            aoff[f][kk] = ma * 128 + (((kk * 64) + g16) ^ (((ma >> 3) & 7) << 4));
            int nb = wn + f * 16 + lrow;
            boff[f][kk] = nb * 128 + (((kk * 64) + g16) ^ ((nb & 7) << 4));
        }

    f32x4 zero4 = {0.f, 0.f, 0.f, 0.f};
    f32x4 acc[4][4];
#pragma unroll
    for (int i = 0; i < 4; ++i)
#pragma unroll
        for (int j = 0; j < 4; ++j) acc[i][j] = zero4;

    uint4 ra[4];
#pragma unroll
    for (int r = 0; r < 4; ++r) ra[r] = *(const uint4*)(pa + (size_t)r * E);
    {
        const ushort* u0 = (const ushort*)&ra[0];
        const ushort* u1 = (const ushort*)&ra[1];
        const ushort* u2 = (const ushort*)&ra[2];
        const ushort* u3 = (const ushort*)&ra[3];
#pragma unroll
        for (int i = 0; i < 8; ++i) {
            uint2 wv;
            wv.x = (unsigned)u0[i] | ((unsigned)u1[i] << 16);
            wv.y = (unsigned)u2[i] | ((unsigned)u3[i] << 16);
            *(uint2*)(lA[0] + abase + i * 128) = wv;
        }
#pragma unroll
        for (int i = 0; i < 4; ++i)
            gload16(gB + (size_t)i * 8 * NP, lB[0] + ldstB + i * 1024);
    }
    pa += (size_t)64 * E;
#pragma unroll
    for (int r = 0; r < 4; ++r) ra[r] = *(const uint4*)(pa + (size_t)r * E);
    __syncthreads();

    for (int kt = 0; kt < NSTEP; ++kt) {
        const int cur = kt & 1;
        if (kt + 1 < NSTEP) {
            const ushort* u0 = (const ushort*)&ra[0];
            const ushort* u1 = (const ushort*)&ra[1];
            const ushort* u2 = (const ushort*)&ra[2];
            const ushort* u3 = (const ushort*)&ra[3];
#pragma unroll
            for (int i = 0; i < 8; ++i) {
                uint2 wv;
                wv.x = (unsigned)u0[i] | ((unsigned)u1[i] << 16);
                wv.y = (unsigned)u2[i] | ((unsigned)u3[i] << 16);
                *(uint2*)(lA[cur ^ 1] + abase + i * 128) = wv;
            }
            const int koff = (kt + 1) * 64;
#pragma unroll
            for (int i = 0; i < 4; ++i)
                gload16(gB + (size_t)i * 8 * NP + koff, lB[cur ^ 1] + ldstB + i * 1024);
        }
        if (kt + 2 < NSTEP) {
            pa += (size_t)64 * E;
#pragma unroll
            for (int r = 0; r < 4; ++r) ra[r] = *(const uint4*)(pa + (size_t)r * E);
        }
#pragma unroll
        for (int kk = 0; kk < 2; ++kk) {
            bf16x8 av[4], bv[4];
#pragma unroll
            for (int f = 0; f < 4; ++f) av[f] = *(const bf16x8*)(lA[cur] + aoff[f][kk]);
#pragma unroll
            for (int f = 0; f < 4; ++f) bv[f] = *(const bf16x8*)(lB[cur] + boff[f][kk]);
#pragma unroll
            for (int i = 0; i < 4; ++i)
#pragma unroll
                for (int j = 0; j < 4; ++j)
                    acc[i][j] = __builtin_amdgcn_mfma_f32_16x16x32_bf16(av[i], bv[j], acc[i][j], 0, 0, 0);
        }
        if (kt + 1 < NSTEP) __syncthreads();
    }
    float* plane = tB + (size_t)ks * E * F;
    const int orow = (lane >> 4) * 4, ocol = lane & 15;
#pragma unroll
    for (int i = 0; i < 4; ++i)
#pragma unroll
        for (int j = 0; j < 4; ++j) {
            int gm = m0 + wm + i * 16 + orow;
            int gn = wn + j * 16 + ocol;
#pragma unroll
            for (int q = 0; q < 4; ++q)
                plane[(size_t)(gm + q) * F + gn] = acc[i][j][q];
        }
}

// ---------------- gemmC (MFMA): C2P[ks][n][f] = sum_{e in chunk} Hbs[n][e] * tsT[f][e] -----
__global__ __launch_bounds__(256) void k_gemmC(const ushort* __restrict__ Hbs,
                                               const ushort* __restrict__ tsT,
                                               float* __restrict__ C2P) {
    __shared__ __align__(16) char lA[2][16384];
    __shared__ __align__(16) char lB[2][16384];
    const int tid = threadIdx.x;
    const int qq_ = 78, rr_ = 4;                     // 628 = 8*78 + 4
    const int xcd = blockIdx.x & 7, idx = blockIdx.x >> 3;
    const int sw = (xcd < rr_ ? xcd * (qq_ + 1) : rr_ * (qq_ + 1) + (xcd - rr_) * qq_) + idx;
    const int m0 = (sw % 157) * 128;
    const int ks = sw / 157;
    const int k0 = ks * 2048;
    const int lane = tid & 63, w = tid >> 6;
    const int wm = (w & 1) * 64, wn = (w >> 1) * 64;
    const int lrow = lane & 15, g16 = (lane >> 4) * 16;
    const int NSTEP = 32;

    const int row8 = lane >> 3, ch8 = lane & 7;
    const ushort* gA = Hbs + (size_t)(m0 + w * 32 + row8) * E + k0 + ((ch8 ^ row8) * 8);
    const ushort* gB = tsT + (size_t)(w * 32 + row8) * E + k0 + ((ch8 ^ row8) * 8);
    const int ldst = w * 32 * 128;

    int aoff[4][2], boff[4][2];
#pragma unroll
    for (int f = 0; f < 4; ++f)
#pragma unroll
        for (int kk = 0; kk < 2; ++kk) {
            int ma = wm + f * 16 + lrow;
            aoff[f][kk] = ma * 128 + (((kk * 64) + g16) ^ ((ma & 7) << 4));
            int nb = wn + f * 16 + lrow;
            boff[f][kk] = nb * 128 + (((kk * 64) + g16) ^ ((nb & 7) << 4));
        }

    f32x4 zero4 = {0.f, 0.f, 0.f, 0.f};
    f32x4 acc[4][4];
#pragma unroll
    for (int i = 0; i < 4; ++i)
#pragma unroll
        for (int j = 0; j < 4; ++j) acc[i][j] = zero4;

#pragma unroll
    for (int i = 0; i < 4; ++i) {
        gload16(gA + (size_t)i * 8 * E, lA[0] + ldst + i * 1024);
        gload16(gB + (size_t)i * 8 * E, lB[0] + ldst + i * 1024);
    }
    __syncthreads();

    for (int kt = 0; kt < NSTEP; ++kt) {
        const int cur = kt & 1;
        if (kt + 1 < NSTEP) {
            const int koff = (kt + 1) * 64;
#pragma unroll
            for (int i = 0; i < 4; ++i) {
                gload16(gA + (size_t)i * 8 * E + koff, lA[cur ^ 1] + ldst + i * 1024);
                gload16(gB + (size_t)i * 8 * E + koff, lB[cur ^ 1] + ldst + i * 1024);
            }
        }
#pragma unroll
        for (int kk = 0; kk < 2; ++kk) {
            bf16x8 av[4], bv[4];
#pragma unroll
            for (int f = 0; f < 4; ++f) av[f] = *(const bf16x8*)(lA[cur] + aoff[f][kk]);
#pragma unroll
            for (int f = 0; f < 4; ++f) bv[f] = *(const bf16x8*)(lB[cur] + boff[f][kk]);
#pragma unroll
            for (int i = 0; i < 4; ++i)
#pragma unroll
                for (int j = 0; j < 4; ++j)
                    acc[i][j] = __builtin_amdgcn_mfma_f32_16x16x32_bf16(av[i], bv[j], acc[i][j], 0, 0, 0);
        }
        if (kt + 1 < NSTEP) __syncthreads();
    }
    float* plane = C2P + (size_t)ks * NP2 * F;
    const int orow = (lane >> 4) * 4, ocol = lane & 15;
#pragma unroll
    for (int i = 0; i < 4; ++i)
#pragma unroll
        for (int j = 0; j < 4; ++j) {
            int gm = m0 + wm + i * 16 + orow;
            int gn = wn + j * 16 + ocol;
#pragma unroll
            for (int q = 0; q < 4; ++q)
                plane[(size_t)(gm + q) * F + gn] = acc[i][j][q];
        }
}

// ---------------- out = gelu(sum_ks C2P[ks][n][f])   (dvis folded into Hbs) ----------------
__global__ void k_fin_out(const float* __restrict__ C2P, float* __restrict__ out) {
    int i4 = blockIdx.x * 256 + threadIdx.x;
    if (i4 < N * F / 4) {
        float4 v = make_float4(0.f, 0.f, 0.f, 0.f);
#pragma unroll
        for (int ks = 0; ks < KS_C; ++ks) {
            float4 p = reinterpret_cast<const float4*>(C2P + (size_t)ks * NP2 * F)[i4];
            v.x += p.x; v.y += p.y; v.z += p.z; v.w += p.w;
        }
        float4 o;
        o.x = gelu_erf(v.x);
        o.y = gelu_erf(v.y);
        o.z = gelu_erf(v.z);
        o.w = gelu_erf(v.w);
        reinterpret_cast<float4*>(out)[i4] = o;
    }
}

extern "C" void kernel_launch(void* const* d_in, const int* in_sizes, int n_in,
                              void* d_out, int out_size, void* d_ws, size_t ws_size,
                              hipStream_t stream) {
    const float* x     = (const float*)d_in[0];
    const float* H     = (const float*)d_in[1];
    const float* W     = (const float*)d_in[2];
    const float* lin_w = (const float*)d_in[3];
    const float* lin_b = (const float*)d_in[4];
    float* out = (float*)d_out;

    // workspace layout (bytes): ~451 MiB
    char* ws = (char*)d_ws;
    ushort* Hbs = (ushort*)ws;                                   // NP*E*2      = 335,544,320
    ushort* yT  = (ushort*)(ws + 335544320);                     // F*NP*2      = 5,242,880
    float*  tB  = (float*) (ws + 340787200);                     // 8*E*F*4     = 33,554,432
    ushort* tsT = (ushort*)(ws + 374341632);                     // F*E*2       = 2,097,152
    float*  C2P = (float*) (ws + 376438784);                     // 4*NP2*F*4   = 41,156,608
    float*  DeP = (float*) (ws + 417595392);                     // 1024*E*4    = 33,554,432
    float*  se  = (float*) (ws + 451149824);                     // E*4

    k_prep_xw<<<PREP_BLOCKS + XW_BLOCKS, 256, 0, stream>>>(H, DeP, Hbs, x, lin_w, lin_b, yT);
    k_gemmB<<<SE_BLOCKS + 64 * KS_B, 256, 0, stream>>>(Hbs, yT, tB, DeP, W, se);
    k_tst<<<(E / 64) * 2, 256, 0, stream>>>(tB, se, tsT);
    k_gemmC<<<157 * KS_C, 256, 0, stream>>>(Hbs, tsT, C2P);
    k_fin_out<<<(N * F / 4 + 255) / 256, 256, 0, stream>>>(C2P, out);
}

// Round 13
// 445.755 us; speedup vs baseline: 2.3596x; 2.3596x over previous
//
#include <hip/hip_runtime.h>
#include <math.h>

static constexpr int N = 20000;       // nodes
static constexpr int E = 8192;        // hyperedges
static constexpr int F = 128;         // feature dim
static constexpr int NP = 20480;      // padded node count (2048*10)
static constexpr int NP2 = 20096;     // padded node count for gemmC output planes (157*128)
static constexpr int PREP_BLOCKS = 2048;  // 10 rows each; blocks >= 2000 are pad
static constexpr int XW_BLOCKS = NP / 8;  // 2560, 8 rows each
static constexpr int KS_B = 8;        // gemmB split-K
static constexpr int KS_C = 4;        // gemmC split-K

typedef short bf16x8 __attribute__((ext_vector_type(8)));
typedef float f32x4 __attribute__((ext_vector_type(4)));

__device__ __forceinline__ float gelu_erf(float x) {
    return 0.5f * x * (1.0f + erff(x * 0.70710678118654752440f));
}
__device__ __forceinline__ unsigned f2bf(float f) {
    unsigned u = __float_as_uint(f);
    return (u + 0x7FFFu + ((u >> 16) & 1u)) >> 16;
}
// async global->LDS, 16B per lane (global source per-lane, LDS dest = base + lane*16)
__device__ __forceinline__ void gload16(const void* g, void* lds) {
    __builtin_amdgcn_global_load_lds(
        (const __attribute__((address_space(1))) unsigned int*)g,
        (__attribute__((address_space(3))) unsigned int*)lds, 16, 0, 0);
}

// ---------------- fused: prep (blocks 0..2047) + xw->yT (blocks 2048..4607) ----------------
// prep: stream H -> Hbs = bf16(H) UNSCALED + Dv row sums. No col-accum, no per-row barrier,
// no scale dependency -> low VGPR, high occupancy, max memory-level parallelism.
// xw: y = bf16(x@lw^T + b) (unscaled), transposed in LDS, written to yT.
__global__ __launch_bounds__(256) void k_prep_xw(const float* __restrict__ H,
                                                 float* __restrict__ Dv,
                                                 ushort* __restrict__ Hbs,
                                                 const float* __restrict__ x,
                                                 const float* __restrict__ lin_w,
                                                 const float* __restrict__ lin_b,
                                                 ushort* __restrict__ yT) {
    __shared__ __align__(16) char smem[4096];
    const int tid = threadIdx.x;

    if (blockIdx.x < PREP_BLOCKS) {
        // ================= prep =================
        const int lane = tid & 63, wid = tid >> 6;
        const int r0 = blockIdx.x * 10;
        if (r0 >= N) {        // pad rows [N, NP): Hbs = 0
            uint4 z = make_uint4(0, 0, 0, 0);
            for (int r = 0; r < 10; ++r) {
                ushort* orow = Hbs + (size_t)(r0 + r) * E;
#pragma unroll
                for (int j = 0; j < 4; ++j) *(uint4*)(orow + (j * 256 + tid) * 8) = z;
            }
            return;
        }
        float (*rp)[4] = (float(*)[4])smem;    // [10][4]
        for (int r = 0; r < 10; ++r) {
            const float* row = H + (size_t)(r0 + r) * E;
            ushort* orow = Hbs + (size_t)(r0 + r) * E;
            float rs = 0.f;
#pragma unroll
            for (int j = 0; j < 4; ++j) {
                const float* base = row + (j * 256 + tid) * 8;   // 32B contiguous per thread
                float4 va = *(const float4*)(base);
                float4 vb = *(const float4*)(base + 4);
                rs += (va.x + va.y) + (va.z + va.w);
                rs += (vb.x + vb.y) + (vb.z + vb.w);
                uint4 o;
                o.x = f2bf(va.x) | (f2bf(va.y) << 16);
                o.y = f2bf(va.z) | (f2bf(va.w) << 16);
                o.z = f2bf(vb.x) | (f2bf(vb.y) << 16);
                o.w = f2bf(vb.z) | (f2bf(vb.w) << 16);
                *(uint4*)(orow + (j * 256 + tid) * 8) = o;       // 16B contiguous store
            }
#pragma unroll
            for (int off = 32; off > 0; off >>= 1) rs += __shfl_xor(rs, off, 64);
            if (lane == 0) rp[r][wid] = rs;
        }
        __syncthreads();       // single barrier per block (10 rows)
        if (tid < 10) Dv[r0 + tid] = rp[tid][0] + rp[tid][1] + rp[tid][2] + rp[tid][3];
    } else {
        // ================= xw -> yT (unscaled; dvis applied later in k_yscale) ============
        const int bxx = blockIdx.x - PREP_BLOCKS;
        const int r0 = bxx * 8;
        if (r0 >= N) {        // pad cols of yT
            if (tid < 128) {
                uint4 z = make_uint4(0, 0, 0, 0);
                *(uint4*)(yT + (size_t)tid * NP + r0) = z;
            }
            return;
        }
        float* xs = (float*)smem;              // [8][128] fp32
#pragma unroll
        for (int c = 0; c < 4; ++c) {
            int lin = c * 256 + tid;
            xs[lin] = x[(size_t)r0 * F + lin];
        }
        __syncthreads();
        const int f = tid & 127, half = tid >> 7;    // rows half*4 .. half*4+3
        float b = lin_b[f];
        float a0 = b, a1 = b, a2 = b, a3 = b;
        const float* xr = xs + (half * 4) * F;
        const float* lwr = lin_w + (size_t)f * F;
#pragma unroll 4
        for (int k = 0; k < F; k += 4) {
            float4 lw = *(const float4*)(lwr + k);
            a0 += xr[0 * F + k] * lw.x; a0 += xr[0 * F + k + 1] * lw.y;
            a0 += xr[0 * F + k + 2] * lw.z; a0 += xr[0 * F + k + 3] * lw.w;
            a1 += xr[1 * F + k] * lw.x; a1 += xr[1 * F + k + 1] * lw.y;
            a1 += xr[1 * F + k + 2] * lw.z; a1 += xr[1 * F + k + 3] * lw.w;
            a2 += xr[2 * F + k] * lw.x; a2 += xr[2 * F + k + 1] * lw.y;
            a2 += xr[2 * F + k + 2] * lw.z; a2 += xr[2 * F + k + 3] * lw.w;
            a3 += xr[3 * F + k] * lw.x; a3 += xr[3 * F + k + 1] * lw.y;
            a3 += xr[3 * F + k + 2] * lw.z; a3 += xr[3 * F + k + 3] * lw.w;
        }
        __syncthreads();                        // all xs reads done
        ushort* tile = (ushort*)smem;           // [8][128] bf16
        tile[(half * 4 + 0) * F + f] = (ushort)f2bf(a0);
        tile[(half * 4 + 1) * F + f] = (ushort)f2bf(a1);
        tile[(half * 4 + 2) * F + f] = (ushort)f2bf(a2);
        tile[(half * 4 + 3) * F + f] = (ushort)f2bf(a3);
        __syncthreads();
        if (tid < 128) {
            unsigned u[4];
#pragma unroll
            for (int qq = 0; qq < 4; ++qq) {
                ushort lo = tile[(qq * 2 + 0) * F + tid];
                ushort hi = tile[(qq * 2 + 1) * F + tid];
                u[qq] = (unsigned)lo | ((unsigned)hi << 16);
            }
            uint4 o = make_uint4(u[0], u[1], u[2], u[3]);
            *(uint4*)(yT + (size_t)tid * NP + r0) = o;
        }
    }
}

// ---------------- yT[f][v] *= dvis[v]  (in-place bf16 scale; needs Dv -> own launch) -------
__global__ void k_yscale(ushort* __restrict__ yT, const float* __restrict__ Dv) {
    size_t g = (size_t)blockIdx.x * 256 + threadIdx.x;   // group of 8 elements
    size_t off = g * 8;
    int v = (int)(off % NP);                              // groups never straddle N (8 | N)
    uint4 u = *(uint4*)(yT + off);
    float s[8];
    if (v < N) {
        float4 d0 = *(const float4*)(Dv + v);
        float4 d1 = *(const float4*)(Dv + v + 4);
        s[0] = rsqrtf(fmaxf(d0.x, 1.f)); s[1] = rsqrtf(fmaxf(d0.y, 1.f));
        s[2] = rsqrtf(fmaxf(d0.z, 1.f)); s[3] = rsqrtf(fmaxf(d0.w, 1.f));
        s[4] = rsqrtf(fmaxf(d1.x, 1.f)); s[5] = rsqrtf(fmaxf(d1.y, 1.f));
        s[6] = rsqrtf(fmaxf(d1.z, 1.f)); s[7] = rsqrtf(fmaxf(d1.w, 1.f));
    } else {
#pragma unroll
        for (int q = 0; q < 8; ++q) s[q] = 0.f;
    }
    unsigned wv[4] = {u.x, u.y, u.z, u.w};
    uint4 o;
    unsigned* ov = &o.x;
#pragma unroll
    for (int p = 0; p < 4; ++p) {
        float lo = __uint_as_float(wv[p] << 16) * s[p * 2];
        float hi = __uint_as_float(wv[p] & 0xFFFF0000u) * s[p * 2 + 1];
        ov[p] = f2bf(lo) | (f2bf(hi) << 16);
    }
    *(uint4*)(yT + off) = o;
}

// ---------------- tsT[f][e] = bf16(se[e] * sum_ks tB[ks][e][f]);  se inline from DeP2 ------
__global__ void k_tst(const float* __restrict__ tB, const float* __restrict__ DeP2,
                      const float* __restrict__ W, ushort* __restrict__ tsT) {
    __shared__ __align__(16) char tl[8192];
    int tid = threadIdx.x;
    int r0 = (blockIdx.x >> 1) * 64;   // e
    int c0 = (blockIdx.x & 1) * 64;    // f
#pragma unroll
    for (int c = 0; c < 4; ++c) {
        int lin = c * 256 + tid;
        int row = lin >> 4, ch = lin & 15;
        size_t base = (size_t)(r0 + row) * F + c0 + ch * 4;
        float4 v = make_float4(0.f, 0.f, 0.f, 0.f);
#pragma unroll
        for (int ks = 0; ks < KS_B; ++ks) {
            float4 p = *(const float4*)(tB + (size_t)ks * E * F + base);
            v.x += p.x; v.y += p.y; v.z += p.z; v.w += p.w;
        }
        float d = 0.f;
#pragma unroll
        for (int ks = 0; ks < KS_B; ++ks) d += DeP2[(size_t)ks * E + r0 + row];
        float s = W[r0 + row] / fmaxf(d, 1.f);
        ushort4 b;
        b.x = (ushort)f2bf(v.x * s); b.y = (ushort)f2bf(v.y * s);
        b.z = (ushort)f2bf(v.z * s); b.w = (ushort)f2bf(v.w * s);
        int key = ((row ^ (row >> 3)) & 7) << 4;
        *(ushort4*)(tl + row * 128 + ((ch * 8) ^ key)) = b;
    }
    __syncthreads();
#pragma unroll
    for (int c = 0; c < 2; ++c) {
        int lin = c * 256 + tid;
        int fl = lin >> 3, vch = lin & 7;
        unsigned u[4];
#pragma unroll
        for (int qq = 0; qq < 4; ++qq) {
            int r1 = vch * 8 + qq * 2, r2 = r1 + 1;
            ushort a = *(const ushort*)(tl + r1 * 128 + ((fl * 2) ^ (((r1 ^ (r1 >> 3)) & 7) << 4)));
            ushort b = *(const ushort*)(tl + r2 * 128 + ((fl * 2) ^ (((r2 ^ (r2 >> 3)) & 7) << 4)));
            u[qq] = (unsigned)a | ((unsigned)b << 16);
        }
        uint4 o = make_uint4(u[0], u[1], u[2], u[3]);
        *(uint4*)(tsT + (size_t)(c0 + fl) * E + r0 + vch * 8) = o;
    }
}

// ---------------- gemmB: tB[ks][e][f] = sum_v Hbs[v][e] * yT[f][v]; De via ones-MFMA -------
__global__ __launch_bounds__(256) void k_gemmB(const ushort* __restrict__ Hbs,
                                               const ushort* __restrict__ yT,
                                               float* __restrict__ tB,
                                               float* __restrict__ DeP2) {
    __shared__ __align__(16) char lA[2][16384];   // As[e 128][v 64] bf16, key ((e>>3)&7)<<4
    __shared__ __align__(16) char lB[2][16384];   // Bs[f 128][v 64] bf16, key (f&7)<<4
    const int tid = threadIdx.x;
    const int sw = (blockIdx.x & 7) * 64 + (blockIdx.x >> 3);   // bijective (512 % 8 == 0)
    const int m0 = (sw & 63) * 128;    // e tile
    const int ks = sw >> 6;
    const int k0 = ks * 2560;          // v chunk
    const int lane = tid & 63, w = tid >> 6;
    const int wm = (w & 1) * 64, wn = (w >> 1) * 64;
    const int lrow = lane & 15, g16 = (lane >> 4) * 16;
    const int NSTEP = 40;

    const int vq = tid >> 4;
    const int e8 = (tid & 15) * 8;
    const ushort* pa = Hbs + (size_t)(k0 + vq * 4) * E + m0 + e8;
    const int abase = e8 * 128 + ((vq * 8) ^ ((tid & 7) << 4));

    const int row8 = lane >> 3, ch8 = lane & 7;
    const ushort* gB = yT + (size_t)(w * 32 + row8) * NP + k0 + ((ch8 ^ row8) * 8);
    const int ldstB = w * 32 * 128;

    int aoff[4][2], boff[4][2];
#pragma unroll
    for (int f = 0; f < 4; ++f)
#pragma unroll
        for (int kk = 0; kk < 2; ++kk) {
            int ma = wm + f * 16 + lrow;
            aoff[f][kk] = ma * 128 + (((kk * 64) + g16) ^ (((ma >> 3) & 7) << 4));
            int nb = wn + f * 16 + lrow;
            boff[f][kk] = nb * 128 + (((kk * 64) + g16) ^ ((nb & 7) << 4));
        }

    f32x4 zero4 = {0.f, 0.f, 0.f, 0.f};
    f32x4 acc[4][4];
    f32x4 deacc[4];
    const short oneb = (short)0x3F80;
    bf16x8 ones = {oneb, oneb, oneb, oneb, oneb, oneb, oneb, oneb};
#pragma unroll
    for (int i = 0; i < 4; ++i) {
        deacc[i] = zero4;
#pragma unroll
        for (int j = 0; j < 4; ++j) acc[i][j] = zero4;
    }

    uint4 ra[4];
#pragma unroll
    for (int r = 0; r < 4; ++r) ra[r] = *(const uint4*)(pa + (size_t)r * E);
    {
        const ushort* u0 = (const ushort*)&ra[0];
        const ushort* u1 = (const ushort*)&ra[1];
        const ushort* u2 = (const ushort*)&ra[2];
        const ushort* u3 = (const ushort*)&ra[3];
#pragma unroll
        for (int i = 0; i < 8; ++i) {
            uint2 wv;
            wv.x = (unsigned)u0[i] | ((unsigned)u1[i] << 16);
            wv.y = (unsigned)u2[i] | ((unsigned)u3[i] << 16);
            *(uint2*)(lA[0] + abase + i * 128) = wv;
        }
#pragma unroll
        for (int i = 0; i < 4; ++i)
            gload16(gB + (size_t)i * 8 * NP, lB[0] + ldstB + i * 1024);
    }
    pa += (size_t)64 * E;
#pragma unroll
    for (int r = 0; r < 4; ++r) ra[r] = *(const uint4*)(pa + (size_t)r * E);
    __syncthreads();

    for (int kt = 0; kt < NSTEP; ++kt) {
        const int cur = kt & 1;
        if (kt + 1 < NSTEP) {
            const ushort* u0 = (const ushort*)&ra[0];
            const ushort* u1 = (const ushort*)&ra[1];
            const ushort* u2 = (const ushort*)&ra[2];
            const ushort* u3 = (const ushort*)&ra[3];
#pragma unroll
            for (int i = 0; i < 8; ++i) {
                uint2 wv;
                wv.x = (unsigned)u0[i] | ((unsigned)u1[i] << 16);
                wv.y = (unsigned)u2[i] | ((unsigned)u3[i] << 16);
                *(uint2*)(lA[cur ^ 1] + abase + i * 128) = wv;
            }
            const int koff = (kt + 1) * 64;
#pragma unroll
            for (int i = 0; i < 4; ++i)
                gload16(gB + (size_t)i * 8 * NP + koff, lB[cur ^ 1] + ldstB + i * 1024);
        }
        if (kt + 2 < NSTEP) {
            pa += (size_t)64 * E;
#pragma unroll
            for (int r = 0; r < 4; ++r) ra[r] = *(const uint4*)(pa + (size_t)r * E);
        }
#pragma unroll
        for (int kk = 0; kk < 2; ++kk) {
            bf16x8 av[4], bv[4];
#pragma unroll
            for (int f = 0; f < 4; ++f) av[f] = *(const bf16x8*)(lA[cur] + aoff[f][kk]);
#pragma unroll
            for (int f = 0; f < 4; ++f) bv[f] = *(const bf16x8*)(lB[cur] + boff[f][kk]);
#pragma unroll
            for (int i = 0; i < 4; ++i)
                deacc[i] = __builtin_amdgcn_mfma_f32_16x16x32_bf16(av[i], ones, deacc[i], 0, 0, 0);
#pragma unroll
            for (int i = 0; i < 4; ++i)
#pragma unroll
                for (int j = 0; j < 4; ++j)
                    acc[i][j] = __builtin_amdgcn_mfma_f32_16x16x32_bf16(av[i], bv[j], acc[i][j], 0, 0, 0);
        }
        if (kt + 1 < NSTEP) __syncthreads();
    }
    float* plane = tB + (size_t)ks * E * F;
    const int orow = (lane >> 4) * 4, ocol = lane & 15;
#pragma unroll
    for (int i = 0; i < 4; ++i)
#pragma unroll
        for (int j = 0; j < 4; ++j) {
            int gm = m0 + wm + i * 16 + orow;
            int gn = wn + j * 16 + ocol;
#pragma unroll
            for (int q = 0; q < 4; ++q)
                plane[(size_t)(gm + q) * F + gn] = acc[i][j][q];
        }
    // De partials: deacc rows = e-row sums over this v-chunk (cols identical).
    // waves 2,3 duplicate waves 0,1 (same wm); lanes with ocol==0 hold rows (lane>>4)*4+q.
    if (w < 2 && ocol == 0) {
        float* dep = DeP2 + (size_t)ks * E + m0 + wm + orow;
#pragma unroll
        for (int i = 0; i < 4; ++i)
            *(f32x4*)(dep + i * 16) = deacc[i];
    }
}

// ---------------- gemmC (MFMA): C2P[ks][n][f] = sum_{e in chunk} Hbs[n][e] * tsT[f][e] -----
__global__ __launch_bounds__(256) void k_gemmC(const ushort* __restrict__ Hbs,
                                               const ushort* __restrict__ tsT,
                                               float* __restrict__ C2P) {
    __shared__ __align__(16) char lA[2][16384];
    __shared__ __align__(16) char lB[2][16384];
    const int tid = threadIdx.x;
    const int qq_ = 78, rr_ = 4;                     // 628 = 8*78 + 4
    const int xcd = blockIdx.x & 7, idx = blockIdx.x >> 3;
    const int sw = (xcd < rr_ ? xcd * (qq_ + 1) : rr_ * (qq_ + 1) + (xcd - rr_) * qq_) + idx;
    const int m0 = (sw % 157) * 128;
    const int ks = sw / 157;
    const int k0 = ks * 2048;
    const int lane = tid & 63, w = tid >> 6;
    const int wm = (w & 1) * 64, wn = (w >> 1) * 64;
    const int lrow = lane & 15, g16 = (lane >> 4) * 16;
    const int NSTEP = 32;

    const int row8 = lane >> 3, ch8 = lane & 7;
    const ushort* gA = Hbs + (size_t)(m0 + w * 32 + row8) * E + k0 + ((ch8 ^ row8) * 8);
    const ushort* gB = tsT + (size_t)(w * 32 + row8) * E + k0 + ((ch8 ^ row8) * 8);
    const int ldst = w * 32 * 128;

    int aoff[4][2], boff[4][2];
#pragma unroll
    for (int f = 0; f < 4; ++f)
#pragma unroll
        for (int kk = 0; kk < 2; ++kk) {
            int ma = wm + f * 16 + lrow;
            aoff[f][kk] = ma * 128 + (((kk * 64) + g16) ^ ((ma & 7) << 4));
            int nb = wn + f * 16 + lrow;
            boff[f][kk] = nb * 128 + (((kk * 64) + g16) ^ ((nb & 7) << 4));
        }

    f32x4 zero4 = {0.f, 0.f, 0.f, 0.f};
    f32x4 acc[4][4];
#pragma unroll
    for (int i = 0; i < 4; ++i)
#pragma unroll
        for (int j = 0; j < 4; ++j) acc[i][j] = zero4;

#pragma unroll
    for (int i = 0; i < 4; ++i) {
        gload16(gA + (size_t)i * 8 * E, lA[0] + ldst + i * 1024);
        gload16(gB + (size_t)i * 8 * E, lB[0] + ldst + i * 1024);
    }
    __syncthreads();

    for (int kt = 0; kt < NSTEP; ++kt) {
        const int cur = kt & 1;
        if (kt + 1 < NSTEP) {
            const int koff = (kt + 1) * 64;
#pragma unroll
            for (int i = 0; i < 4; ++i) {
                gload16(gA + (size_t)i * 8 * E + koff, lA[cur ^ 1] + ldst + i * 1024);
                gload16(gB + (size_t)i * 8 * E + koff, lB[cur ^ 1] + ldst + i * 1024);
            }
        }
#pragma unroll
        for (int kk = 0; kk < 2; ++kk) {
            bf16x8 av[4], bv[4];
#pragma unroll
            for (int f = 0; f < 4; ++f) av[f] = *(const bf16x8*)(lA[cur] + aoff[f][kk]);
#pragma unroll
            for (int f = 0; f < 4; ++f) bv[f] = *(const bf16x8*)(lB[cur] + boff[f][kk]);
#pragma unroll
            for (int i = 0; i < 4; ++i)
#pragma unroll
                for (int j = 0; j < 4; ++j)
                    acc[i][j] = __builtin_amdgcn_mfma_f32_16x16x32_bf16(av[i], bv[j], acc[i][j], 0, 0, 0);
        }
        if (kt + 1 < NSTEP) __syncthreads();
    }
    float* plane = C2P + (size_t)ks * NP2 * F;
    const int orow = (lane >> 4) * 4, ocol = lane & 15;
#pragma unroll
    for (int i = 0; i < 4; ++i)
#pragma unroll
        for (int j = 0; j < 4; ++j) {
            int gm = m0 + wm + i * 16 + orow;
            int gn = wn + j * 16 + ocol;
#pragma unroll
            for (int q = 0; q < 4; ++q)
                plane[(size_t)(gm + q) * F + gn] = acc[i][j][q];
        }
}

// ---------------- out = gelu(dvis[n] * sum_ks C2P[ks][n][f]) ----------------
__global__ void k_fin_out(const float* __restrict__ C2P, const float* __restrict__ Dv,
                          float* __restrict__ out) {
    int i4 = blockIdx.x * 256 + threadIdx.x;
    if (i4 < N * F / 4) {
        int n = i4 >> 5;
        float s = rsqrtf(fmaxf(Dv[n], 1.f));
        float4 v = make_float4(0.f, 0.f, 0.f, 0.f);
#pragma unroll
        for (int ks = 0; ks < KS_C; ++ks) {
            float4 p = reinterpret_cast<const float4*>(C2P + (size_t)ks * NP2 * F)[i4];
            v.x += p.x; v.y += p.y; v.z += p.z; v.w += p.w;
        }
        float4 o;
        o.x = gelu_erf(s * v.x);
        o.y = gelu_erf(s * v.y);
        o.z = gelu_erf(s * v.z);
        o.w = gelu_erf(s * v.w);
        reinterpret_cast<float4*>(out)[i4] = o;
    }
}

extern "C" void kernel_launch(void* const* d_in, const int* in_sizes, int n_in,
                              void* d_out, int out_size, void* d_ws, size_t ws_size,
                              hipStream_t stream) {
    const float* x     = (const float*)d_in[0];
    const float* H     = (const float*)d_in[1];
    const float* W     = (const float*)d_in[2];
    const float* lin_w = (const float*)d_in[3];
    const float* lin_b = (const float*)d_in[4];
    float* out = (float*)d_out;

    // workspace layout (bytes): ~399 MiB
    char* ws = (char*)d_ws;
    ushort* Hbs  = (ushort*)ws;                                  // NP*E*2      = 335,544,320
    ushort* yT   = (ushort*)(ws + 335544320);                    // F*NP*2      = 5,242,880
    float*  tB   = (float*) (ws + 340787200);                    // 8*E*F*4     = 33,554,432
    ushort* tsT  = (ushort*)(ws + 374341632);                    // F*E*2       = 2,097,152
    float*  C2P  = (float*) (ws + 376438784);                    // 4*NP2*F*4   = 41,156,608
    float*  DeP2 = (float*) (ws + 417595392);                    // 8*E*4       = 262,144
    float*  Dv   = (float*) (ws + 417857536);                    // NP*4        = 81,920

    k_prep_xw<<<PREP_BLOCKS + XW_BLOCKS, 256, 0, stream>>>(H, Dv, Hbs, x, lin_w, lin_b, yT);
    k_yscale<<<(F * NP / 8) / 256, 256, 0, stream>>>(yT, Dv);
    k_gemmB<<<64 * KS_B, 256, 0, stream>>>(Hbs, yT, tB, DeP2);
    k_tst<<<(E / 64) * 2, 256, 0, stream>>>(tB, DeP2, W, tsT);
    k_gemmC<<<157 * KS_C, 256, 0, stream>>>(Hbs, tsT, C2P);
    k_fin_out<<<(N * F / 4 + 255) / 256, 256, 0, stream>>>(C2P, Dv, out);
}